// Round 9
// baseline (91.300 us; speedup 1.0000x reference)
//
#include <hip/hip_runtime.h>

#define NPTS 4096
#define NBATCH 16
#define THREADS 256
#define QPB 256          // queries per block (4 waves x 64)
#define TH 2             // target halves (occupancy split)
#define TGH (NPTS / TH)  // 2048 targets per block
#define TCH 512          // targets per LDS chunk
#define NCH (TGH / TCH)  // 4 chunks
#define NBLK_B 512

typedef __attribute__((ext_vector_type(8))) short short8;
typedef __attribute__((ext_vector_type(16))) float float16v;

static __device__ __forceinline__ unsigned short f2bf(float f) {
  unsigned int u = __builtin_bit_cast(unsigned int, f);
  u = (u + 0x7FFFu + ((u >> 16) & 1u)) >> 16;  // RNE
  return (unsigned short)u;
}
static __device__ __forceinline__ float bf2f(unsigned short h) {
  unsigned int u = ((unsigned int)h) << 16;
  return __builtin_bit_cast(float, u);
}
// Swizzled ushort offset of half-record h of target j (32B flat records,
// XOR 16B-block bits by j's 128B-group bits): staging writes and B-frag
// reads both cover all 32 banks per 8-lane phase (R8: conflict-free).
static __device__ __forceinline__ int toff(int j, int h) {
  return (j * 16 + h * 8) ^ (((j >> 2) & 7) << 3);
}
#define WSIDX(b, dir, th, q) (((((b)*2 + (dir)) * 2 + (th)) << 12) + (q))

// Chamfer, fp32, B=16, N=M=4096, d=3, bf16-split 32x32x16 MFMA (layouts and
// split verified: R8 absmax 0.0). d2 emitted directly by the MFMA:
//   A (query): [uhx,uhx,ulx, uhy,uhy,uly, uhz,uhz,ulz, 1,1, p2h,p2l, 0,0,0]
//   B (target):[thx,tlx,thx, thy,tly,thy, thz,tlz,thz, t2h,t2l, 1,1, 0,0,0]
// where u=-2p; sum_k A[k]B[k] = |p|^2 - 2p.t + |t|^2 = d2.
// Kernel A: grid (16qc x 2th, 16, 2) = 1024 blocks -> 4 blocks/CU,
// 4 waves/SIMD (R8 at 2 waves/SIMD was latency-exposed: ~35us vs ~6us issue
// work). Wave owns 64 queries (2 A-frags), scans its 2048-target half in 4
// LDS chunks; per tp: 2 ds_read_b128, 4 MFMA, 32 v_min3. Writes per-(query,
// th) min-d2 to ws. Kernel B: min over th, sqrt, ticket-reduce -> out.
__global__ __launch_bounds__(THREADS)
__attribute__((amdgpu_waves_per_eu(4, 4)))
void chamfer_mfma(const float* __restrict__ shape,
                  const float* __restrict__ tmpl,
                  float* __restrict__ ws,
                  unsigned int* __restrict__ ticket) {
  __shared__ unsigned short tgt[TCH * 16];  // 16 KB swizzled records
  __shared__ unsigned short qry[QPB * 16];  // 8 KB flat records

  if (blockIdx.x == 0 && blockIdx.y == 0 && blockIdx.z == 0 && threadIdx.x == 0)
    *ticket = 0u;  // consumed by kernel B (stream-ordered)

  const int qc = blockIdx.x >> 1;
  const int th = blockIdx.x & 1;
  const int b = blockIdx.y;
  const int dir = blockIdx.z;
  const float* Pb = (dir == 0 ? shape : tmpl) + (size_t)b * NPTS * 3;
  const float* Tb = (dir == 0 ? tmpl : shape) + (size_t)b * NPTS * 3;

  const int tid = threadIdx.x;
  const int lane = tid & 63;
  const int wave = tid >> 6;
  const int n = lane & 31;   // MFMA row/col
  const int kg = lane >> 5;  // K-group: k = kg*8 + j

  // ---- Stage 256 queries: u=-2p split + p2 split record ----
  {
    const int qg = qc * QPB + tid;
    const float px = Pb[3 * qg + 0], py = Pb[3 * qg + 1], pz = Pb[3 * qg + 2];
    const float ux = -2.0f * px, uy = -2.0f * py, uz = -2.0f * pz;
    const float p2 = fmaf(px, px, fmaf(py, py, pz * pz));
    const unsigned short hx = f2bf(ux), hy = f2bf(uy), hz = f2bf(uz);
    const unsigned short lx = f2bf(ux - bf2f(hx)), ly = f2bf(uy - bf2f(hy)),
                         lz = f2bf(uz - bf2f(hz));
    const unsigned short h2 = f2bf(p2), l2 = f2bf(p2 - bf2f(h2));
    const unsigned short ONE = 0x3F80;
    short8 v0, v1;
    v0[0] = hx; v0[1] = hx; v0[2] = lx; v0[3] = hy;
    v0[4] = hy; v0[5] = ly; v0[6] = hz; v0[7] = hz;
    v1[0] = lz; v1[1] = ONE; v1[2] = ONE; v1[3] = h2;
    v1[4] = l2; v1[5] = 0;  v1[6] = 0;  v1[7] = 0;
    *(short8*)&qry[tid * 16] = v0;
    *(short8*)&qry[tid * 16 + 8] = v1;
  }
  __syncthreads();

  const short8 af0 = *(const short8*)&qry[(wave * 64 + n) * 16 + kg * 8];
  const short8 af1 = *(const short8*)&qry[(wave * 64 + 32 + n) * 16 + kg * 8];

  const float INF = 3.402823466e38f;
  float acc0[16], acc1[16];
  #pragma unroll
  for (int r = 0; r < 16; ++r) { acc0[r] = INF; acc1[r] = INF; }
  const float16v z = {};

  const float4* T4 = (const float4*)Tb;
  for (int ch = 0; ch < NCH; ++ch) {
    __syncthreads();
    // ---- Stage 512 targets (threads 0..127: 4 each via 3 float4 loads) ----
    if (tid < TCH / 4) {
      const int g = th * (TGH / 4) + ch * (TCH / 4) + tid;
      const float4 a = T4[g * 3 + 0];
      const float4 c = T4[g * 3 + 1];
      const float4 d = T4[g * 3 + 2];
      const float X[4] = {a.x, a.w, c.z, d.y};
      const float Y[4] = {a.y, c.x, c.w, d.z};
      const float Z[4] = {a.z, c.y, d.x, d.w};
      #pragma unroll
      for (int p = 0; p < 4; ++p) {
        const float x = X[p], y = Y[p], zc = Z[p];
        const float t2 = fmaf(x, x, fmaf(y, y, zc * zc));
        const unsigned short hx = f2bf(x), hy = f2bf(y), hz = f2bf(zc);
        const unsigned short lx = f2bf(x - bf2f(hx)), ly = f2bf(y - bf2f(hy)),
                             lz = f2bf(zc - bf2f(hz));
        const unsigned short h2 = f2bf(t2), l2 = f2bf(t2 - bf2f(h2));
        const unsigned short ONE = 0x3F80;
        short8 v0, v1;
        v0[0] = hx; v0[1] = lx; v0[2] = hx; v0[3] = hy;
        v0[4] = ly; v0[5] = hy; v0[6] = hz; v0[7] = lz;
        v1[0] = hz; v1[1] = h2; v1[2] = l2; v1[3] = ONE;
        v1[4] = ONE; v1[5] = 0; v1[6] = 0; v1[7] = 0;
        const int j = tid * 4 + p;
        *(short8*)&tgt[toff(j, 0)] = v0;
        *(short8*)&tgt[toff(j, 1)] = v1;
      }
    }
    __syncthreads();

    // ---- 8 tile-pairs: 2 reads -> 2x(2 MFMA + 16 min3) ----
    #pragma unroll 2
    for (int tp = 0; tp < TCH / 64; ++tp) {
      const short8 b0 = *(const short8*)&tgt[toff(tp * 64 + n, kg)];
      const short8 b1 = *(const short8*)&tgt[toff(tp * 64 + 32 + n, kg)];
      {
        float16v d0 = __builtin_amdgcn_mfma_f32_32x32x16_bf16(af0, b0, z, 0, 0, 0);
        float16v d1 = __builtin_amdgcn_mfma_f32_32x32x16_bf16(af0, b1, z, 0, 0, 0);
        #pragma unroll
        for (int r = 0; r < 16; ++r)
          acc0[r] = fminf(fminf(d0[r], d1[r]), acc0[r]);  // v_min3_f32
      }
      {
        float16v d0 = __builtin_amdgcn_mfma_f32_32x32x16_bf16(af1, b0, z, 0, 0, 0);
        float16v d1 = __builtin_amdgcn_mfma_f32_32x32x16_bf16(af1, b1, z, 0, 0, 0);
        #pragma unroll
        for (int r = 0; r < 16; ++r)
          acc1[r] = fminf(fminf(d0[r], d1[r]), acc1[r]);
      }
    }
  }

  // ---- Min across the 32 cols within each half-wave ----
  #pragma unroll
  for (int m = 1; m <= 16; m <<= 1) {
    #pragma unroll
    for (int r = 0; r < 16; ++r) {
      acc0[r] = fminf(acc0[r], __shfl_xor(acc0[r], m, 64));
      acc1[r] = fminf(acc1[r], __shfl_xor(acc1[r], m, 64));
    }
  }

  // ---- Lanes 0 / 32 hold disjoint row sets: write per-query min d2 ----
  if (n == 0) {
    const int qbase = qc * QPB + wave * 64;
    const int wsb = WSIDX(b, dir, th, 0);
    #pragma unroll
    for (int r = 0; r < 16; ++r) {
      const int row = (r & 3) + 8 * (r >> 2) + 4 * kg;
      ws[wsb + qbase + row] = acc0[r];
      ws[wsb + qbase + 32 + row] = acc1[r];
    }
  }
}

__global__ __launch_bounds__(THREADS) void chamfer_combine(
    const float* __restrict__ ws, float* __restrict__ partials,
    unsigned int* __restrict__ ticket, float* __restrict__ out) {
  __shared__ float red[4];
  __shared__ bool amLast;
  const int g = blockIdx.x * THREADS + threadIdx.x;  // 0..131071
  const int b = g >> 13;
  const int dir = (g >> 12) & 1;
  const int q = g & 4095;

  const float m = fminf(ws[WSIDX(b, dir, 0, q)], ws[WSIDX(b, dir, 1, q)]);
  float s = sqrtf(fmaxf(m, 0.0f));

  #pragma unroll
  for (int off = 32; off > 0; off >>= 1) s += __shfl_down(s, off, 64);
  const int lane = threadIdx.x & 63;
  const int wid = threadIdx.x >> 6;
  if (lane == 0) red[wid] = s;
  __syncthreads();
  if (threadIdx.x == 0) {
    partials[blockIdx.x] = red[0] + red[1] + red[2] + red[3];
    __threadfence();  // release
    unsigned int t = atomicAdd(ticket, 1u);
    amLast = (t == (unsigned int)(gridDim.x - 1));
  }
  __syncthreads();
  if (amLast) {
    __threadfence();  // acquire
    float v = partials[threadIdx.x] + partials[threadIdx.x + THREADS];
    #pragma unroll
    for (int off = 32; off > 0; off >>= 1) v += __shfl_down(v, off, 64);
    if (lane == 0) red[wid] = v;
    __syncthreads();
    if (threadIdx.x == 0)
      out[0] = (red[0] + red[1] + red[2] + red[3]) * (0.01f / 16.0f);
  }
}

// ---- Fallback (known-correct round-2 kernel) if ws is too small ----
__global__ __launch_bounds__(THREADS) void chamfer_fallback(
    const float* __restrict__ shape, const float* __restrict__ tmpl,
    float* __restrict__ out) {
  __shared__ float4 tile[NPTS];
  const int b = blockIdx.y;
  const int dir = blockIdx.z;
  const float* Pb = (dir == 0 ? shape : tmpl) + (size_t)b * NPTS * 3;
  const float* Tb = (dir == 0 ? tmpl : shape) + (size_t)b * NPTS * 3;
  const float4* T4 = (const float4*)Tb;
  for (int base = threadIdx.x * 4; base < NPTS; base += THREADS * 4) {
    const int k = base >> 2;
    float4 a = T4[3 * k + 0], c = T4[3 * k + 1], d = T4[3 * k + 2];
    tile[base + 0] = make_float4(a.x, a.y, a.z, 0.5f * fmaf(a.x, a.x, fmaf(a.y, a.y, a.z * a.z)));
    tile[base + 1] = make_float4(a.w, c.x, c.y, 0.5f * fmaf(a.w, a.w, fmaf(c.x, c.x, c.y * c.y)));
    tile[base + 2] = make_float4(c.z, c.w, d.x, 0.5f * fmaf(c.z, c.z, fmaf(c.w, c.w, d.x * d.x)));
    tile[base + 3] = make_float4(d.y, d.z, d.w, 0.5f * fmaf(d.y, d.y, fmaf(d.z, d.z, d.w * d.w)));
  }
  __syncthreads();
  const int m0 = blockIdx.x * (THREADS * 2) + threadIdx.x;
  const int m1 = m0 + THREADS;
  const float qx0 = Pb[3 * m0], qy0 = Pb[3 * m0 + 1], qz0 = Pb[3 * m0 + 2];
  const float qx1 = Pb[3 * m1], qy1 = Pb[3 * m1 + 1], qz1 = Pb[3 * m1 + 2];
  const float nx0 = -qx0, ny0 = -qy0, nz0 = -qz0;
  const float nx1 = -qx1, ny1 = -qy1, nz1 = -qz1;
  const float p20 = fmaf(qx0, qx0, fmaf(qy0, qy0, qz0 * qz0));
  const float p21 = fmaf(qx1, qx1, fmaf(qy1, qy1, qz1 * qz1));
  const float INF = 3.402823466e38f;
  float a00 = INF, a01 = INF, a10 = INF, a11 = INF;
  #pragma unroll 2
  for (int n = 0; n < NPTS; n += 2) {
    float4 t0 = tile[n], t1 = tile[n + 1];
    a00 = fminf(a00, fmaf(nx0, t0.x, fmaf(ny0, t0.y, fmaf(nz0, t0.z, t0.w))));
    a10 = fminf(a10, fmaf(nx1, t0.x, fmaf(ny1, t0.y, fmaf(nz1, t0.z, t0.w))));
    a01 = fminf(a01, fmaf(nx0, t1.x, fmaf(ny0, t1.y, fmaf(nz0, t1.z, t1.w))));
    a11 = fminf(a11, fmaf(nx1, t1.x, fmaf(ny1, t1.y, fmaf(nz1, t1.z, t1.w))));
  }
  float s = sqrtf(fmaxf(fmaf(2.0f, fminf(a00, a01), p20), 0.0f)) +
            sqrtf(fmaxf(fmaf(2.0f, fminf(a10, a11), p21), 0.0f));
  #pragma unroll
  for (int off = 32; off > 0; off >>= 1) s += __shfl_down(s, off, 64);
  __syncthreads();
  float* red = (float*)tile;
  if ((threadIdx.x & 63) == 0) red[threadIdx.x >> 6] = s;
  __syncthreads();
  if (threadIdx.x == 0)
    atomicAdd(out, (red[0] + red[1] + red[2] + red[3]) * (0.01f / 16.0f));
}

extern "C" void kernel_launch(void* const* d_in, const int* in_sizes, int n_in,
                              void* d_out, int out_size, void* d_ws, size_t ws_size,
                              hipStream_t stream) {
  const float* shape = (const float*)d_in[0];
  const float* tmpl = (const float*)d_in[1];
  float* out = (float*)d_out;

  const size_t ws_mins = (size_t)NBATCH * 2 * TH * NPTS * sizeof(float);  // 1 MB
  const size_t ws_needed = ws_mins + NBLK_B * sizeof(float) + sizeof(unsigned int);
  if (ws_size >= ws_needed) {
    float* ws_part = (float*)d_ws;
    float* partials = (float*)((char*)d_ws + ws_mins);
    unsigned int* ticket = (unsigned int*)(partials + NBLK_B);
    dim3 gridA(16 * TH, NBATCH, 2);
    chamfer_mfma<<<gridA, dim3(THREADS), 0, stream>>>(shape, tmpl, ws_part, ticket);
    chamfer_combine<<<dim3(NBLK_B), dim3(THREADS), 0, stream>>>(
        ws_part, partials, ticket, out);
  } else {
    hipMemsetAsync(out, 0, sizeof(float) * out_size, stream);
    dim3 grid(NPTS / (THREADS * 2), NBATCH, 2);
    chamfer_fallback<<<grid, dim3(THREADS), 0, stream>>>(shape, tmpl, out);
  }
}

// Round 10
// 81.332 us; speedup vs baseline: 1.1226x; 1.1226x over previous
//
#include <hip/hip_runtime.h>

#define NPTS 4096
#define NBATCH 16
#define THREADS 256
#define QPB 128          // queries per block (4 waves x 32; 1 A-frag/wave)
#define TCH 1024         // targets per LDS chunk
#define NCH (NPTS / TCH) // 4 chunks

typedef __attribute__((ext_vector_type(8))) short short8;
typedef __attribute__((ext_vector_type(16))) float float16v;

static __device__ __forceinline__ unsigned short f2bf(float f) {
  unsigned int u = __builtin_bit_cast(unsigned int, f);
  u = (u + 0x7FFFu + ((u >> 16) & 1u)) >> 16;  // RNE
  return (unsigned short)u;
}
static __device__ __forceinline__ float bf2f(unsigned short h) {
  unsigned int u = ((unsigned int)h) << 16;
  return __builtin_bit_cast(float, u);
}
// Swizzled ushort offset of half-record h of target j (32B flat records,
// 16B-block XOR keyed by j's 128B group) -- staging writes & B-frag reads
// land on distinct banks (R8: verified correct, absmax 0.0).
static __device__ __forceinline__ int toff(int j, int h) {
  return (j * 16 + h * 8) ^ (((j >> 2) & 7) << 3);
}

// Chamfer, fp32, B=16, N=M=4096, d=3, bf16-split 32x32x16 MFMA.
// d2 emitted directly by the MFMA (K=13 of 16 slots; verified R9 absmax 0.0):
//   A (query): [uhx,uhx,ulx, uhy,uhy,uly, uhz,uhz,ulz, 1,1, p2h,p2l, 0*3]
//   B (target):[thx,tlx,thx, thy,tly,thy, thz,tlz,thz, t2h,t2l, 1,1, 0*3]
// with u=-2p: sum_k A[k]B[k] = |p|^2 - 2p.t + |t|^2.
// R10 change: 1 A-frag/wave (32 queries) so live regs ~90 < 128 -> clean
// 4 blocks/CU, 4 waves/SIMD occupancy WITHOUT spills (R9 split demanded 4
// waves at ~140 live regs -> spill suspected; R8 at 2 waves was latency-
// exposed: ~35us vs ~6us issue floor). Grid (32,16,2)=1024 blocks; block
// scans all 4096 targets in 4 LDS chunks; per tp: 2 ds_read_b128, 2 MFMA,
// 16 v_min3. Single kernel, atomicAdd epilogue, no workspace.
__global__ __launch_bounds__(THREADS)
__attribute__((amdgpu_waves_per_eu(4, 4)))
void chamfer_mfma(const float* __restrict__ shape,
                  const float* __restrict__ tmpl,
                  float* __restrict__ out) {
  __shared__ unsigned short tgt[TCH * 16];  // 32 KB swizzled records
  __shared__ unsigned short qry[QPB * 16];  // 4 KB flat records
  __shared__ float redbuf[4];

  const int qc = blockIdx.x;
  const int b = blockIdx.y;
  const int dir = blockIdx.z;
  const float* Pb = (dir == 0 ? shape : tmpl) + (size_t)b * NPTS * 3;
  const float* Tb = (dir == 0 ? tmpl : shape) + (size_t)b * NPTS * 3;

  const int tid = threadIdx.x;
  const int lane = tid & 63;
  const int wave = tid >> 6;
  const int n = lane & 31;   // MFMA row/col
  const int kg = lane >> 5;  // K-group: k = kg*8 + j

  // ---- Stage 128 queries: u=-2p split + p2 split record ----
  if (tid < QPB) {
    const int qg = qc * QPB + tid;
    const float px = Pb[3 * qg + 0], py = Pb[3 * qg + 1], pz = Pb[3 * qg + 2];
    const float ux = -2.0f * px, uy = -2.0f * py, uz = -2.0f * pz;
    const float p2 = fmaf(px, px, fmaf(py, py, pz * pz));
    const unsigned short hx = f2bf(ux), hy = f2bf(uy), hz = f2bf(uz);
    const unsigned short lx = f2bf(ux - bf2f(hx)), ly = f2bf(uy - bf2f(hy)),
                         lz = f2bf(uz - bf2f(hz));
    const unsigned short h2 = f2bf(p2), l2 = f2bf(p2 - bf2f(h2));
    const unsigned short ONE = 0x3F80;
    short8 v0, v1;
    v0[0] = hx; v0[1] = hx; v0[2] = lx; v0[3] = hy;
    v0[4] = hy; v0[5] = ly; v0[6] = hz; v0[7] = hz;
    v1[0] = lz; v1[1] = ONE; v1[2] = ONE; v1[3] = h2;
    v1[4] = l2; v1[5] = 0;  v1[6] = 0;  v1[7] = 0;
    *(short8*)&qry[tid * 16] = v0;
    *(short8*)&qry[tid * 16 + 8] = v1;
  }
  __syncthreads();

  // ---- One A-frag: wave w owns queries w*32 .. w*32+31 ----
  const short8 af = *(const short8*)&qry[(wave * 32 + n) * 16 + kg * 8];

  const float INF = 3.402823466e38f;
  float acc[16];
  #pragma unroll
  for (int r = 0; r < 16; ++r) acc[r] = INF;
  const float16v z = {};

  const float4* T4 = (const float4*)Tb;
  for (int ch = 0; ch < NCH; ++ch) {
    __syncthreads();
    // ---- Stage 1024 targets (4/thread: 3 float4 loads -> swizzled recs) ----
    {
      const int g = ch * (TCH / 4) + tid;
      const float4 a = T4[g * 3 + 0];
      const float4 c = T4[g * 3 + 1];
      const float4 d = T4[g * 3 + 2];
      const float X[4] = {a.x, a.w, c.z, d.y};
      const float Y[4] = {a.y, c.x, c.w, d.z};
      const float Z[4] = {a.z, c.y, d.x, d.w};
      #pragma unroll
      for (int p = 0; p < 4; ++p) {
        const float x = X[p], y = Y[p], zc = Z[p];
        const float t2 = fmaf(x, x, fmaf(y, y, zc * zc));
        const unsigned short hx = f2bf(x), hy = f2bf(y), hz = f2bf(zc);
        const unsigned short lx = f2bf(x - bf2f(hx)), ly = f2bf(y - bf2f(hy)),
                             lz = f2bf(zc - bf2f(hz));
        const unsigned short h2 = f2bf(t2), l2 = f2bf(t2 - bf2f(h2));
        const unsigned short ONE = 0x3F80;
        short8 v0, v1;
        v0[0] = hx; v0[1] = lx; v0[2] = hx; v0[3] = hy;
        v0[4] = ly; v0[5] = hy; v0[6] = hz; v0[7] = lz;
        v1[0] = hz; v1[1] = h2; v1[2] = l2; v1[3] = ONE;
        v1[4] = ONE; v1[5] = 0; v1[6] = 0; v1[7] = 0;
        const int j = tid * 4 + p;
        *(short8*)&tgt[toff(j, 0)] = v0;
        *(short8*)&tgt[toff(j, 1)] = v1;
      }
    }
    __syncthreads();

    // ---- 16 tile-pairs: 2 reads -> 2 MFMA -> 16 min3 ----
    for (int tp = 0; tp < TCH / 64; ++tp) {
      const short8 b0 = *(const short8*)&tgt[toff(tp * 64 + n, kg)];
      const short8 b1 = *(const short8*)&tgt[toff(tp * 64 + 32 + n, kg)];
      float16v d0 = __builtin_amdgcn_mfma_f32_32x32x16_bf16(af, b0, z, 0, 0, 0);
      float16v d1 = __builtin_amdgcn_mfma_f32_32x32x16_bf16(af, b1, z, 0, 0, 0);
      #pragma unroll
      for (int r = 0; r < 16; ++r)
        acc[r] = fminf(fminf(d0[r], d1[r]), acc[r]);  // v_min3_f32
    }
  }

  // ---- Min across the 32 cols within each kg half ----
  #pragma unroll
  for (int m = 1; m <= 16; m <<= 1) {
    #pragma unroll
    for (int r = 0; r < 16; ++r)
      acc[r] = fminf(acc[r], __shfl_xor(acc[r], m, 64));
  }

  // ---- Epilogue: lanes 0/32 hold disjoint row sets; sqrt+reduce+atomic ----
  float s = 0.0f;
  if (n == 0) {
    #pragma unroll
    for (int r = 0; r < 16; ++r)
      s += sqrtf(fmaxf(acc[r], 0.0f));
  }
  s += __shfl_xor(s, 32, 64);  // combine kg=0 / kg=1 partial sums
  if (lane == 0) redbuf[wave] = s;
  __syncthreads();
  if (tid == 0) {
    // out = 0.01 * mean over 16 batches of per-batch chamfer sums
    atomicAdd(out, (redbuf[0] + redbuf[1] + redbuf[2] + redbuf[3]) * (0.01f / 16.0f));
  }
}

extern "C" void kernel_launch(void* const* d_in, const int* in_sizes, int n_in,
                              void* d_out, int out_size, void* d_ws, size_t ws_size,
                              hipStream_t stream) {
  const float* shape = (const float*)d_in[0];
  const float* tmpl = (const float*)d_in[1];
  float* out = (float*)d_out;

  // d_out is poisoned to 0xAA before every timed launch; atomics need zeros.
  hipMemsetAsync(out, 0, sizeof(float) * out_size, stream);

  dim3 grid(NPTS / QPB, NBATCH, 2);
  chamfer_mfma<<<grid, dim3(THREADS), 0, stream>>>(shape, tmpl, out);
}